// Round 9
// baseline (97.300 us; speedup 1.0000x reference)
//
#include <hip/hip_runtime.h>
#include <stdint.h>

typedef __attribute__((ext_vector_type(8))) short s16x8;
typedef __attribute__((ext_vector_type(4))) float f32x4;

__device__ __forceinline__ short f2bf(float f){
  union { float f; uint32_t u; } v; v.f = f;
  uint32_t u = v.u;
  u += 0x7fffu + ((u >> 16) & 1u);
  return (short)(u >> 16);
}
__device__ __forceinline__ float sigm_fast(float x){
  float e = __builtin_amdgcn_exp2f(x * -1.44269504f);
  return __builtin_amdgcn_rcpf(1.f + e);
}
__device__ __forceinline__ float tanh_fast(float x){
  float e = __builtin_amdgcn_exp2f(x * 2.88539008f);
  return __builtin_fmaf(-2.f, __builtin_amdgcn_rcpf(e + 1.f), 1.f);
}

#define MFMA16(a, b, c) __builtin_amdgcn_mfma_f32_16x16x32_bf16((a), (b), (c), 0, 0, 0)

// Fused TemporalEncoder. Round-9: dual-stream PHASE-SHIFTED pipeline.
// M=32 (streams A,B of 16 seqs), grid=256, 1 block/CU, 4 waves.
// Per barrier-interval each wave runs: MFMA phase of one stream (held in regs
// across the barrier) + elementwise phase of the OTHER stream -- independent
// work for the matrix and VALU pipes inside each wave, halving the exposed
// serial chain vs lockstep (r6/r8: ~600cy path, ~1000cy stall/step).
// Convs batched per 16-step chunk (r8 structure), both streams per phase.
__global__ __launch_bounds__(256, 1) void te_fused(
    const float* __restrict__ x,
    const float* __restrict__ w1, const float* __restrict__ b1,
    const float* __restrict__ w2, const float* __restrict__ b2,
    const float* __restrict__ Wih, const float* __restrict__ Whh,
    const float* __restrict__ bih, const float* __restrict__ bhh,
    float* __restrict__ out)
{
  __shared__ float x_s[32 * 100];       // 12800 B
  __shared__ short hS[2][2][16 * 72];   // [stream][buf][seq][72-pad dim] 9216 B
  __shared__ short c1b[2][16 * 328];    // [stream][seq][19 tau][16 ch] 20992 B
  __shared__ short s_b[2][16 * 640];    // [stream][t][seq][40-pad ch] 40960 B

  const int tid  = threadIdx.x;
  const int lane = tid & 63;
  const int wv   = tid >> 6;
  const int l15  = lane & 15;
  const int lg   = lane >> 4;
  const int seq0 = blockIdx.x * 32;

  // ---- stage x (32*100 floats) ----
  {
    const float4* gx = reinterpret_cast<const float4*>(x + (size_t)seq0 * 100);
    float4* sx = reinterpret_cast<float4*>(x_s);
    for (int i = tid; i < 800; i += 256) sx[i] = gx[i];
  }
  // zero h buf0 of both streams
  {
    int* p = reinterpret_cast<int*>(&hS[0][0][0]);
    for (int i = tid; i < 576; i += 256) p[i] = 0;
    int* q = reinterpret_cast<int*>(&hS[1][0][0]);
    for (int i = tid; i < 576; i += 256) q[i] = 0;
  }

  // ---- GRU weight B-fragments (shared by both streams) ----
  s16x8 WhhHi[3][2], WihHi[3];
  f32x4 bias_r, bias_z, bias_xn, bias_hn;
#pragma unroll
  for (int g = 0; g < 3; ++g) {
    const int n = 64 * g + 16 * wv + l15;
#pragma unroll
    for (int ks = 0; ks < 2; ++ks) {
      const float* p = Whh + n * 64 + ks * 32 + lg * 8;
#pragma unroll
      for (int j = 0; j < 8; ++j) WhhHi[g][ks][j] = f2bf(p[j]);
    }
    const float* q = Wih + n * 32 + lg * 8;
#pragma unroll
    for (int j = 0; j < 8; ++j) WihHi[g][j] = f2bf(q[j]);
    float bi = bih[n], bh = bhh[n];
    if (g == 0) { float v = bi + bh; bias_r  = (f32x4){v, v, v, v}; }
    if (g == 1) { float v = bi + bh; bias_z  = (f32x4){v, v, v, v}; }
    if (g == 2) { bias_xn = (f32x4){bi, bi, bi, bi};
                  bias_hn = (f32x4){bh, bh, bh, bh}; }
  }

  // conv2 role: wave -> stream cq = wv>>1, ch-tile cnt = wv&1, all 16 u.
  const int cq  = wv >> 1;
  const int cnt = wv & 1;
  s16x8 cW2[2];
  f32x4 b2v4;
  {
    const int ch = 16 * cnt + l15;
    float bv = b2[ch];
    b2v4 = (f32x4){bv, bv, bv, bv};
#pragma unroll
    for (int ks = 0; ks < 2; ++ks) {
      s16x8 h8;
#pragma unroll
      for (int j = 0; j < 8; ++j) {
        const int k = ks * 32 + lg * 8 + j;
        const int g = k >> 4, ii = k & 15;
        h8[j] = (g < 3) ? f2bf(w2[ch * 48 + ii * 3 + g]) : (short)0;
      }
      cW2[ks] = h8;
    }
  }

  // conv1: thread -> seq sl (both streams), channel chc
  const int sl  = tid >> 4;
  const int chc = tid & 15;
  const float w1v0 = w1[chc * 3 + 0], w1v1 = w1[chc * 3 + 1], w1v2 = w1[chc * 3 + 2];
  const float b1v = b1[chc];

  // ---- hoisted LDS pointers ----
  const short* sRdA = &s_b[0][0] + l15 * 40 + lg * 8;
  const short* sRdB = &s_b[1][0] + l15 * 40 + lg * 8;
  const short* hRdA = &hS[0][0][0] + l15 * 72 + lg * 8;
  const short* hRdB = &hS[1][0][0] + l15 * 72 + lg * 8;
  short* hWrA = &hS[0][0][0] + (lg * 4) * 72 + 16 * wv + l15;
  short* hWrB = &hS[1][0][0] + (lg * 4) * 72 + 16 * wv + l15;
  const short* c1Rd = &c1b[cq][0] + l15 * 328 + lg * 8;
  short* sWrC = &s_b[cq][0] + (lg * 4) * 40 + cnt * 16 + l15;
  short* c1WrA = &c1b[0][0] + sl * 328 + chc;
  short* c1WrB = &c1b[1][0] + sl * 328 + chc;
  const float* xRdA = &x_s[sl * 100];
  const float* xRdB = &x_s[(sl + 16) * 100];

  __syncthreads();

  float hregA[4] = {0.f, 0.f, 0.f, 0.f};
  float hregB[4] = {0.f, 0.f, 0.f, 0.f};
  f32x4 prA, pzA, xnA, hnA, prB, pzB, xnB, hnB;
  int hOffA = 0, hOffB = 0;      // current read-buf offset (shorts)

#define MPHASE(sPtr_, hBase_, hOff_, PR_, PZ_, XN_, HN_) do {                 \
    s16x8 as_ = *reinterpret_cast<const s16x8*>(sPtr_);                       \
    s16x8 ah0 = *reinterpret_cast<const s16x8*>((hBase_) + (hOff_));          \
    s16x8 ah1 = *reinterpret_cast<const s16x8*>((hBase_) + (hOff_) + 32);     \
    PR_ = MFMA16(as_, WihHi[0],                                               \
          MFMA16(ah1, WhhHi[0][1],                                            \
          MFMA16(ah0, WhhHi[0][0], bias_r)));                                 \
    PZ_ = MFMA16(as_, WihHi[1],                                               \
          MFMA16(ah1, WhhHi[1][1],                                            \
          MFMA16(ah0, WhhHi[1][0], bias_z)));                                 \
    XN_ = MFMA16(as_, WihHi[2], bias_xn);                                     \
    HN_ = MFMA16(ah1, WhhHi[2][1],                                            \
          MFMA16(ah0, WhhHi[2][0], bias_hn));                                 \
  } while (0)

#define EPHASE(PR_, PZ_, XN_, HN_, HREG_, hWr_, hOffW_) do {                  \
    float hnew[4];                                                            \
    _Pragma("unroll")                                                         \
    for (int i2 = 0; i2 < 4; ++i2) {                                          \
      float r = sigm_fast(PR_[i2]);                                           \
      float z = sigm_fast(PZ_[i2]);                                           \
      float tn = tanh_fast(__builtin_fmaf(r, HN_[i2], XN_[i2]));              \
      float h = __builtin_fmaf(z, HREG_[i2] - tn, tn);                        \
      HREG_[i2] = h; hnew[i2] = h;                                            \
    }                                                                         \
    uint32_t p01, p23;                                                        \
    asm("v_cvt_pk_bf16_f32 %0, %1, %2" : "=v"(p01) : "v"(hnew[0]), "v"(hnew[1])); \
    asm("v_cvt_pk_bf16_f32 %0, %1, %2" : "=v"(p23) : "v"(hnew[2]), "v"(hnew[3])); \
    (hWr_)[(hOffW_) +   0] = (short)(p01 & 0xffff);                           \
    (hWr_)[(hOffW_) +  72] = (short)(p01 >> 16);                              \
    (hWr_)[(hOffW_) + 144] = (short)(p23 & 0xffff);                           \
    (hWr_)[(hOffW_) + 216] = (short)(p23 >> 16);                              \
  } while (0)

#pragma unroll 1
  for (int k = 0; k < 7; ++k) {
    const int t0 = k * 16;
    const int NS = (k < 6) ? 16 : 4;

    // ---- conv1 phase: taus t0-2 .. t0+16 for BOTH streams ----
    {
      int xi0 = t0 - 4, xi1 = t0 - 3;
      float xaA = (xi0 < 0) ? 0.f : xRdA[xi0];
      float xbA = (xi1 < 0) ? 0.f : xRdA[xi1];
      float xaB = (xi0 < 0) ? 0.f : xRdB[xi0];
      float xbB = (xi1 < 0) ? 0.f : xRdB[xi1];
#pragma unroll
      for (int i = 0; i < 19; ++i) {
        const int xi = t0 - 2 + i;
        const int idx = xi < 0 ? 0 : (xi > 99 ? 99 : xi);
        float xcA = (xi < 0) ? 0.f : xRdA[idx];
        float xcB = (xi < 0) ? 0.f : xRdB[idx];
        float cA = __builtin_fmaf(w1v0, xaA,
                   __builtin_fmaf(w1v1, xbA,
                   __builtin_fmaf(w1v2, xcA, b1v)));
        cA = cA > 0.f ? cA : 0.f;
        cA = (xi < 0) ? 0.f : cA;
        float cB = __builtin_fmaf(w1v0, xaB,
                   __builtin_fmaf(w1v1, xbB,
                   __builtin_fmaf(w1v2, xcB, b1v)));
        cB = cB > 0.f ? cB : 0.f;
        cB = (xi < 0) ? 0.f : cB;
        uint32_t cu;
        asm("v_cvt_pk_bf16_f32 %0, %1, %2" : "=v"(cu) : "v"(cA), "v"(cB));
        c1WrA[i * 16] = (short)(cu & 0xffff);
        c1WrB[i * 16] = (short)(cu >> 16);
        xaA = xbA; xbA = xcA; xaB = xbB; xbB = xcB;
      }
    }
    __syncthreads();

    // ---- conv2 phase: 16 timesteps for this wave's (stream, ch-tile) ----
#pragma unroll
    for (int u = 0; u < 16; ++u) {
      s16x8 a0 = *reinterpret_cast<const s16x8*>(c1Rd + u * 16);
      s16x8 a1 = *reinterpret_cast<const s16x8*>(c1Rd + u * 16 + 32);
      f32x4 sa = MFMA16(a1, cW2[1], MFMA16(a0, cW2[0], b2v4));
      float m0 = sa[0] > 0.f ? sa[0] : 0.f;
      float m1 = sa[1] > 0.f ? sa[1] : 0.f;
      float m2 = sa[2] > 0.f ? sa[2] : 0.f;
      float m3 = sa[3] > 0.f ? sa[3] : 0.f;
      uint32_t u01, u23;
      asm("v_cvt_pk_bf16_f32 %0, %1, %2" : "=v"(u01) : "v"(m0), "v"(m1));
      asm("v_cvt_pk_bf16_f32 %0, %1, %2" : "=v"(u23) : "v"(m2), "v"(m3));
      sWrC[u * 640 +   0] = (short)(u01 & 0xffff);
      sWrC[u * 640 +  40] = (short)(u01 >> 16);
      sWrC[u * 640 +  80] = (short)(u23 & 0xffff);
      sWrC[u * 640 + 120] = (short)(u23 >> 16);
    }
    __syncthreads();

    // ---- phase-shifted GRU intervals ----
    const short* sA = sRdA;
    const short* sB = sRdB;

    // interval: A-MFMA(0) + B-elem(prev chunk last step)
    MPHASE(sA, hRdA, hOffA, prA, pzA, xnA, hnA); sA += 640;
    if (k > 0) { EPHASE(prB, pzB, xnB, hnB, hregB, hWrB, hOffB ^ 1152); hOffB ^= 1152; }
    __syncthreads();

#pragma unroll 2
    for (int j = 0; j < NS - 1; ++j) {
      // B-MFMA(j) + A-elem(j)
      MPHASE(sB, hRdB, hOffB, prB, pzB, xnB, hnB); sB += 640;
      EPHASE(prA, pzA, xnA, hnA, hregA, hWrA, hOffA ^ 1152); hOffA ^= 1152;
      __syncthreads();
      // A-MFMA(j+1) + B-elem(j)
      MPHASE(sA, hRdA, hOffA, prA, pzA, xnA, hnA); sA += 640;
      EPHASE(prB, pzB, xnB, hnB, hregB, hWrB, hOffB ^ 1152); hOffB ^= 1152;
      __syncthreads();
    }

    // final interval: B-MFMA(NS-1) + A-elem(NS-1)
    MPHASE(sB, hRdB, hOffB, prB, pzB, xnB, hnB);
    EPHASE(prA, pzA, xnA, hnA, hregA, hWrA, hOffA ^ 1152); hOffA ^= 1152;
    __syncthreads();
    // B-elem(NS-1) deferred to next chunk's first interval (or drain below)
  }

  // ---- drain: B-elem(99), registers only ----
#pragma unroll
  for (int i2 = 0; i2 < 4; ++i2) {
    float r = sigm_fast(prB[i2]);
    float z = sigm_fast(pzB[i2]);
    float tn = tanh_fast(__builtin_fmaf(r, hnB[i2], xnB[i2]));
    hregB[i2] = __builtin_fmaf(z, hregB[i2] - tn, tn);
  }

#pragma unroll
  for (int i2 = 0; i2 < 4; ++i2) {
    out[(size_t)(seq0 + lg * 4 + i2) * 64 + 16 * wv + l15] = hregA[i2];
    out[(size_t)(seq0 + 16 + lg * 4 + i2) * 64 + 16 * wv + l15] = hregB[i2];
  }
}

extern "C" void kernel_launch(void* const* d_in, const int* in_sizes, int n_in,
                              void* d_out, int out_size, void* d_ws, size_t ws_size,
                              hipStream_t stream)
{
  (void)in_sizes; (void)n_in; (void)d_ws; (void)ws_size; (void)out_size;
  const float* x   = (const float*)d_in[0];
  const float* w1  = (const float*)d_in[1];
  const float* b1  = (const float*)d_in[2];
  const float* w2  = (const float*)d_in[3];
  const float* b2  = (const float*)d_in[4];
  const float* Wih = (const float*)d_in[5];
  const float* Whh = (const float*)d_in[6];
  const float* bih = (const float*)d_in[7];
  const float* bhh = (const float*)d_in[8];
  float* out = (float*)d_out;
  te_fused<<<256, 256, 0, stream>>>(x, w1, b1, w2, b2, Wih, Whh, bih, bhh, out);
}

// Round 10
// 73.547 us; speedup vs baseline: 1.3230x; 1.3230x over previous
//
#include <hip/hip_runtime.h>
#include <stdint.h>

typedef __attribute__((ext_vector_type(8))) short s16x8;
typedef __attribute__((ext_vector_type(4))) float f32x4;

__device__ __forceinline__ short f2bf(float f){
  union { float f; uint32_t u; } v; v.f = f;
  uint32_t u = v.u;
  u += 0x7fffu + ((u >> 16) & 1u);
  return (short)(u >> 16);
}
__device__ __forceinline__ float sigm_fast(float x){
  float e = __builtin_amdgcn_exp2f(x * -1.44269504f);
  return __builtin_amdgcn_rcpf(1.f + e);
}
__device__ __forceinline__ float tanh_fast(float x){
  float e = __builtin_amdgcn_exp2f(x * 2.88539008f);
  return __builtin_fmaf(-2.f, __builtin_amdgcn_rcpf(e + 1.f), 1.f);
}

#define MFMA16(a, b, c) __builtin_amdgcn_mfma_f32_16x16x32_bf16((a), (b), (c), 0, 0, 0)

// Fused TemporalEncoder. Round-10 = round-8 base (M=16, grid=512, 2 blocks/CU --
// the measured sweet spot; both 1-block/CU variants r7/r9 regressed) plus:
//  * ANTI-CONVOY STAGGER: co-resident blocks are b and b+256 (8-XCD round-robin,
//    2/CU); both run identical per-step code from identical start -> stall
//    windows align and neither block fills the other's gaps. Delay the second
//    cohort by s_sleep(7) (~448cy) at entry; the offset persists (no coupling).
//  * conv1 clamp peel: chunks 1..5 need no edge clamps (saves ~4 VALU x 19/chunk).
__global__ __launch_bounds__(256, 2) void te_fused(
    const float* __restrict__ x,
    const float* __restrict__ w1, const float* __restrict__ b1,
    const float* __restrict__ w2, const float* __restrict__ b2,
    const float* __restrict__ Wih, const float* __restrict__ Whh,
    const float* __restrict__ bih, const float* __restrict__ bhh,
    float* __restrict__ out)
{
  __shared__ float x_s[16 * 100];     // staged input rows (6400 B)
  __shared__ short hA[2][16 * 72];    // [buf][seq][72-pad dim] bf16 h (4608 B)
  __shared__ short c1b[16 * 328];     // [seq][19 tau][16 ch], 328-pad (10496 B)
  __shared__ short s_b[16 * 640];     // [16 t][16 seq][40-pad ch(32)] (20480 B)

  const int tid  = threadIdx.x;
  const int lane = tid & 63;
  const int wv   = tid >> 6;
  const int l15  = lane & 15;
  const int lg   = lane >> 4;
  const int seq0 = blockIdx.x * 16;

  // anti-convoy stagger for the second co-resident cohort
  if ((blockIdx.x >> 8) & 1) __builtin_amdgcn_s_sleep(7);

  // ---- stage x ----
  {
    const float4* gx = reinterpret_cast<const float4*>(x + (size_t)seq0 * 100);
    float4* sx = reinterpret_cast<float4*>(x_s);
    for (int i = tid; i < 400; i += 256) sx[i] = gx[i];
  }
  // zero h buf0
  {
    int* p = reinterpret_cast<int*>(&hA[0][0]);
    for (int i = tid; i < 576; i += 256) p[i] = 0;
  }

  // ---- weight B-fragments ----
  s16x8 WhhHi[3][2], WihHi[3];
  f32x4 bias_r, bias_z, bias_xn, bias_hn;
#pragma unroll
  for (int g = 0; g < 3; ++g) {
    const int n = 64 * g + 16 * wv + l15;
#pragma unroll
    for (int ks = 0; ks < 2; ++ks) {
      const float* p = Whh + n * 64 + ks * 32 + lg * 8;
#pragma unroll
      for (int j = 0; j < 8; ++j) WhhHi[g][ks][j] = f2bf(p[j]);
    }
    const float* q = Wih + n * 32 + lg * 8;
#pragma unroll
    for (int j = 0; j < 8; ++j) WihHi[g][j] = f2bf(q[j]);
    float bi = bih[n], bh = bhh[n];
    if (g == 0) { float v = bi + bh; bias_r  = (f32x4){v, v, v, v}; }
    if (g == 1) { float v = bi + bh; bias_z  = (f32x4){v, v, v, v}; }
    if (g == 2) { bias_xn = (f32x4){bi, bi, bi, bi};
                  bias_hn = (f32x4){bh, bh, bh, bh}; }
  }

  // conv2 B-frags: flat k = ks*32+lg*8+j, group g=k>>4: g<3 -> tap g, g==3 -> 0.
  s16x8 cW2[2];
  f32x4 b2v4;
  {
    const int ch = 16 * (wv & 1) + l15;
    float bv = b2[ch];
    b2v4 = (f32x4){bv, bv, bv, bv};
#pragma unroll
    for (int ks = 0; ks < 2; ++ks) {
      s16x8 h8;
#pragma unroll
      for (int j = 0; j < 8; ++j) {
        const int k = ks * 32 + lg * 8 + j;
        const int g = k >> 4, ii = k & 15;
        h8[j] = (g < 3) ? f2bf(w2[ch * 48 + ii * 3 + g]) : (short)0;
      }
      cW2[ks] = h8;
    }
  }

  // conv1 mapping: all 256 threads, (seq, ch)
  const int sl  = tid >> 4;
  const int chc = tid & 15;
  const float w1v0 = w1[chc * 3 + 0], w1v1 = w1[chc * 3 + 1], w1v2 = w1[chc * 3 + 2];
  const float b1v = b1[chc];

  // ---- hoisted LDS pointers ----
  const short* sRd  = &s_b[0]   + l15 * 40 + lg * 8;
  const short* hRd  = &hA[0][0] + l15 * 72 + lg * 8;
  short*       hWr  = &hA[0][0] + (lg * 4) * 72 + 16 * wv + l15;
  const short* c1Rd = &c1b[0]   + l15 * 328 + lg * 8;
  short*       sWr  = &s_b[0]   + (lg * 4) * 40 + (wv & 1) * 16 + l15;
  short*       c1Wr = &c1b[0]   + sl * 328 + chc;
  const float* xRd  = &x_s[sl * 100];
  const int    ub   = (wv >> 1) * 8;

  __syncthreads();

  float hreg[4] = {0.f, 0.f, 0.f, 0.f};

#define CONV1_PHASE(T0_, CLAMP_) do {                                         \
    float xa, xb;                                                             \
    if (CLAMP_) {                                                             \
      const int xi0 = (T0_) - 4, xi1 = (T0_) - 3;                             \
      xa = (xi0 < 0) ? 0.f : xRd[xi0 < 0 ? 0 : (xi0 > 99 ? 99 : xi0)];        \
      xb = (xi1 < 0) ? 0.f : xRd[xi1 < 0 ? 0 : (xi1 > 99 ? 99 : xi1)];        \
    } else {                                                                  \
      xa = xRd[(T0_) - 4]; xb = xRd[(T0_) - 3];                               \
    }                                                                         \
    _Pragma("unroll")                                                         \
    for (int i = 0; i < 19; ++i) {                                            \
      const int xi = (T0_) - 2 + i;                                           \
      float xc;                                                               \
      if (CLAMP_) {                                                           \
        const int idx = xi < 0 ? 0 : (xi > 99 ? 99 : xi);                     \
        xc = (xi < 0) ? 0.f : xRd[idx];                                       \
      } else {                                                                \
        xc = xRd[xi];                                                         \
      }                                                                       \
      float c = __builtin_fmaf(w1v0, xa,                                      \
                __builtin_fmaf(w1v1, xb,                                      \
                __builtin_fmaf(w1v2, xc, b1v)));                              \
      c = c > 0.f ? c : 0.f;                                                  \
      if (CLAMP_) c = (xi < 0) ? 0.f : c;                                     \
      uint32_t cu;                                                            \
      asm("v_cvt_pk_bf16_f32 %0, %1, %2" : "=v"(cu) : "v"(c), "v"(c));        \
      c1Wr[i * 16] = (short)(cu & 0xffff);                                    \
      xa = xb; xb = xc;                                                       \
    }                                                                         \
  } while (0)

#define CONV2_PHASE() do {                                                    \
    _Pragma("unroll")                                                         \
    for (int i = 0; i < 8; ++i) {                                             \
      const int u = ub + i;                                                   \
      s16x8 a0 = *reinterpret_cast<const s16x8*>(c1Rd + u * 16);              \
      s16x8 a1 = *reinterpret_cast<const s16x8*>(c1Rd + u * 16 + 32);         \
      f32x4 sa = MFMA16(a1, cW2[1], MFMA16(a0, cW2[0], b2v4));                \
      float m0 = sa[0] > 0.f ? sa[0] : 0.f;                                   \
      float m1 = sa[1] > 0.f ? sa[1] : 0.f;                                   \
      float m2 = sa[2] > 0.f ? sa[2] : 0.f;                                   \
      float m3 = sa[3] > 0.f ? sa[3] : 0.f;                                   \
      uint32_t u01, u23;                                                      \
      asm("v_cvt_pk_bf16_f32 %0, %1, %2" : "=v"(u01) : "v"(m0), "v"(m1));     \
      asm("v_cvt_pk_bf16_f32 %0, %1, %2" : "=v"(u23) : "v"(m2), "v"(m3));     \
      sWr[u * 640 +   0] = (short)(u01 & 0xffff);                             \
      sWr[u * 640 +  40] = (short)(u01 >> 16);                                \
      sWr[u * 640 +  80] = (short)(u23 & 0xffff);                             \
      sWr[u * 640 + 120] = (short)(u23 >> 16);                                \
    }                                                                         \
  } while (0)

#define GSTEP(TL) do {                                                        \
    const int rb_ = (TL) & 1, wb_ = rb_ ^ 1;                                  \
    s16x8 as_ = *reinterpret_cast<const s16x8*>(sRd + (TL) * 640);            \
    s16x8 ah0 = *reinterpret_cast<const s16x8*>(hRd + rb_ * 1152);            \
    s16x8 ah1 = *reinterpret_cast<const s16x8*>(hRd + rb_ * 1152 + 32);       \
    __builtin_amdgcn_s_setprio(1);                                            \
    f32x4 pr = MFMA16(as_, WihHi[0],                                          \
               MFMA16(ah1, WhhHi[0][1],                                       \
               MFMA16(ah0, WhhHi[0][0], bias_r)));                            \
    f32x4 pz = MFMA16(as_, WihHi[1],                                          \
               MFMA16(ah1, WhhHi[1][1],                                       \
               MFMA16(ah0, WhhHi[1][0], bias_z)));                            \
    f32x4 xn = MFMA16(as_, WihHi[2], bias_xn);                                \
    f32x4 hn = MFMA16(ah1, WhhHi[2][1],                                       \
               MFMA16(ah0, WhhHi[2][0], bias_hn));                            \
    __builtin_amdgcn_s_setprio(0);                                            \
    float hnew[4];                                                            \
    _Pragma("unroll")                                                         \
    for (int i2 = 0; i2 < 4; ++i2) {                                          \
      float r = sigm_fast(pr[i2]);                                            \
      float z = sigm_fast(pz[i2]);                                            \
      float tn = tanh_fast(__builtin_fmaf(r, hn[i2], xn[i2]));                \
      float h = __builtin_fmaf(z, hreg[i2] - tn, tn);                         \
      hreg[i2] = h; hnew[i2] = h;                                             \
    }                                                                         \
    uint32_t p01, p23;                                                        \
    asm("v_cvt_pk_bf16_f32 %0, %1, %2" : "=v"(p01) : "v"(hnew[0]), "v"(hnew[1])); \
    asm("v_cvt_pk_bf16_f32 %0, %1, %2" : "=v"(p23) : "v"(hnew[2]), "v"(hnew[3])); \
    hWr[wb_ * 1152 +   0] = (short)(p01 & 0xffff);                            \
    hWr[wb_ * 1152 +  72] = (short)(p01 >> 16);                               \
    hWr[wb_ * 1152 + 144] = (short)(p23 & 0xffff);                            \
    hWr[wb_ * 1152 + 216] = (short)(p23 >> 16);                               \
    __syncthreads();                                                          \
  } while (0)

#define G16 do { GSTEP(0);  GSTEP(1);  GSTEP(2);  GSTEP(3);                   \
                 GSTEP(4);  GSTEP(5);  GSTEP(6);  GSTEP(7);                   \
                 GSTEP(8);  GSTEP(9);  GSTEP(10); GSTEP(11);                  \
                 GSTEP(12); GSTEP(13); GSTEP(14); GSTEP(15); } while (0)

  // ---- chunk 0 (edge-clamped conv1) ----
  CONV1_PHASE(0, true);
  __syncthreads();
  CONV2_PHASE();
  __syncthreads();
  G16;

  // ---- chunks 1..5 (no clamps) ----
#pragma unroll 1
  for (int k = 1; k < 6; ++k) {
    const int t0 = k * 16;
    CONV1_PHASE(t0, false);
    __syncthreads();
    CONV2_PHASE();
    __syncthreads();
    G16;
  }

  // ---- chunk 6 (edge-clamped, 4 steps) ----
  CONV1_PHASE(96, true);
  __syncthreads();
  CONV2_PHASE();
  __syncthreads();
  GSTEP(0); GSTEP(1); GSTEP(2); GSTEP(3);

#pragma unroll
  for (int i2 = 0; i2 < 4; ++i2) {
    out[(size_t)(seq0 + lg * 4 + i2) * 64 + 16 * wv + l15] = hreg[i2];
  }
}

extern "C" void kernel_launch(void* const* d_in, const int* in_sizes, int n_in,
                              void* d_out, int out_size, void* d_ws, size_t ws_size,
                              hipStream_t stream)
{
  (void)in_sizes; (void)n_in; (void)d_ws; (void)ws_size; (void)out_size;
  const float* x   = (const float*)d_in[0];
  const float* w1  = (const float*)d_in[1];
  const float* b1  = (const float*)d_in[2];
  const float* w2  = (const float*)d_in[3];
  const float* b2  = (const float*)d_in[4];
  const float* Wih = (const float*)d_in[5];
  const float* Whh = (const float*)d_in[6];
  const float* bih = (const float*)d_in[7];
  const float* bhh = (const float*)d_in[8];
  float* out = (float*)d_out;
  te_fused<<<512, 256, 0, stream>>>(x, w1, b1, w2, b2, Wih, Whh, bih, bhh, out);
}

// Round 11
// 67.739 us; speedup vs baseline: 1.4364x; 1.0857x over previous
//
#include <hip/hip_runtime.h>
#include <stdint.h>

typedef __attribute__((ext_vector_type(8))) short s16x8;
typedef __attribute__((ext_vector_type(4))) float f32x4;

__device__ __forceinline__ short f2bf(float f){
  union { float f; uint32_t u; } v; v.f = f;
  uint32_t u = v.u;
  u += 0x7fffu + ((u >> 16) & 1u);
  return (short)(u >> 16);
}

#define MFMA16(a, b, c) __builtin_amdgcn_mfma_f32_16x16x32_bf16((a), (b), (c), 0, 0, 0)

// Fused TemporalEncoder. Round-11 = round-10 base (M=16, grid=512, 2 blocks/CU,
// batched conv phases per 16-step chunk) with chain/issue trims:
//  * activation scales folded into weights: r/z rows x -log2e, n rows x 2log2e
//    -> sigm = rcp(1+exp2(pre)), tanh = fma(-2, rcp(exp2(arg)+1), 1); kills 12
//    muls/wave/step and one dependent op per transcendental chain.
//  * gate MFMA re-association: s-dependent MFMAs (bias as C) issue first from a
//    PREFETCHED s-fragment; only 2 h-MFMAs chain after the h ds_read.
//  * cross-step s-prefetch (s_b is chunk-constant during G16 -> race-free).
__global__ __launch_bounds__(256, 2) void te_fused(
    const float* __restrict__ x,
    const float* __restrict__ w1, const float* __restrict__ b1,
    const float* __restrict__ w2, const float* __restrict__ b2,
    const float* __restrict__ Wih, const float* __restrict__ Whh,
    const float* __restrict__ bih, const float* __restrict__ bhh,
    float* __restrict__ out)
{
  __shared__ float x_s[16 * 100];     // staged input rows (6400 B)
  __shared__ short hA[2][16 * 72];    // [buf][seq][72-pad dim] bf16 h (4608 B)
  __shared__ short c1b[16 * 328];     // [seq][19 tau][16 ch], 328-pad (10496 B)
  __shared__ short s_b[16 * 640];     // [16 t][16 seq][40-pad ch(32)] (20480 B)

  const int tid  = threadIdx.x;
  const int lane = tid & 63;
  const int wv   = tid >> 6;
  const int l15  = lane & 15;
  const int lg   = lane >> 4;
  const int seq0 = blockIdx.x * 16;

  // anti-convoy stagger (measured neutral, zero cost -- kept)
  if ((blockIdx.x >> 8) & 1) __builtin_amdgcn_s_sleep(7);

  // ---- stage x ----
  {
    const float4* gx = reinterpret_cast<const float4*>(x + (size_t)seq0 * 100);
    float4* sx = reinterpret_cast<float4*>(x_s);
    for (int i = tid; i < 400; i += 256) sx[i] = gx[i];
  }
  // zero h buf0
  {
    int* p = reinterpret_cast<int*>(&hA[0][0]);
    for (int i = tid; i < 576; i += 256) p[i] = 0;
  }

  // ---- weight B-fragments, activation scale FOLDED IN ----
  // g=0 (r), g=1 (z): rows scaled by -log2e  -> gate = rcp(1+exp2(pre))
  // g=2 (n): xn/hn rows scaled by 2*log2e    -> tanh = fma(-2,rcp(exp2(arg)+1),1)
  s16x8 WhhHi[3][2], WihHi[3];
  f32x4 bias_r, bias_z, bias_xn, bias_hn;
#pragma unroll
  for (int g = 0; g < 3; ++g) {
    const float gs = (g < 2) ? -1.44269504f : 2.88539008f;
    const int n = 64 * g + 16 * wv + l15;
#pragma unroll
    for (int ks = 0; ks < 2; ++ks) {
      const float* p = Whh + n * 64 + ks * 32 + lg * 8;
#pragma unroll
      for (int j = 0; j < 8; ++j) WhhHi[g][ks][j] = f2bf(gs * p[j]);
    }
    const float* q = Wih + n * 32 + lg * 8;
#pragma unroll
    for (int j = 0; j < 8; ++j) WihHi[g][j] = f2bf(gs * q[j]);
    float bi = bih[n], bh = bhh[n];
    if (g == 0) { float v = gs * (bi + bh); bias_r = (f32x4){v, v, v, v}; }
    if (g == 1) { float v = gs * (bi + bh); bias_z = (f32x4){v, v, v, v}; }
    if (g == 2) { float vx = gs * bi, vh = gs * bh;
                  bias_xn = (f32x4){vx, vx, vx, vx};
                  bias_hn = (f32x4){vh, vh, vh, vh}; }
  }

  // conv2 B-frags: flat k = ks*32+lg*8+j, group g=k>>4: g<3 -> tap g, g==3 -> 0.
  s16x8 cW2[2];
  f32x4 b2v4;
  {
    const int ch = 16 * (wv & 1) + l15;
    float bv = b2[ch];
    b2v4 = (f32x4){bv, bv, bv, bv};
#pragma unroll
    for (int ks = 0; ks < 2; ++ks) {
      s16x8 h8;
#pragma unroll
      for (int j = 0; j < 8; ++j) {
        const int k = ks * 32 + lg * 8 + j;
        const int g = k >> 4, ii = k & 15;
        h8[j] = (g < 3) ? f2bf(w2[ch * 48 + ii * 3 + g]) : (short)0;
      }
      cW2[ks] = h8;
    }
  }

  // conv1 mapping: all 256 threads, (seq, ch)
  const int sl  = tid >> 4;
  const int chc = tid & 15;
  const float w1v0 = w1[chc * 3 + 0], w1v1 = w1[chc * 3 + 1], w1v2 = w1[chc * 3 + 2];
  const float b1v = b1[chc];

  // ---- hoisted LDS pointers ----
  const short* sRd  = &s_b[0]   + l15 * 40 + lg * 8;
  const short* hRd  = &hA[0][0] + l15 * 72 + lg * 8;
  short*       hWr  = &hA[0][0] + (lg * 4) * 72 + 16 * wv + l15;
  const short* c1Rd = &c1b[0]   + l15 * 328 + lg * 8;
  short*       sWr  = &s_b[0]   + (lg * 4) * 40 + (wv & 1) * 16 + l15;
  short*       c1Wr = &c1b[0]   + sl * 328 + chc;
  const float* xRd  = &x_s[sl * 100];
  const int    ub   = (wv >> 1) * 8;

  __syncthreads();

  float hreg[4] = {0.f, 0.f, 0.f, 0.f};
  s16x8 asv;                      // prefetched s A-frag for the current step

#define CONV1_PHASE(T0_, CLAMP_) do {                                         \
    float xa, xb;                                                             \
    if (CLAMP_) {                                                             \
      const int xi0 = (T0_) - 4, xi1 = (T0_) - 3;                             \
      xa = (xi0 < 0) ? 0.f : xRd[xi0 < 0 ? 0 : (xi0 > 99 ? 99 : xi0)];        \
      xb = (xi1 < 0) ? 0.f : xRd[xi1 < 0 ? 0 : (xi1 > 99 ? 99 : xi1)];        \
    } else {                                                                  \
      xa = xRd[(T0_) - 4]; xb = xRd[(T0_) - 3];                               \
    }                                                                         \
    _Pragma("unroll")                                                         \
    for (int i = 0; i < 19; ++i) {                                            \
      const int xi = (T0_) - 2 + i;                                           \
      float xc;                                                               \
      if (CLAMP_) {                                                           \
        const int idx = xi < 0 ? 0 : (xi > 99 ? 99 : xi);                     \
        xc = (xi < 0) ? 0.f : xRd[idx];                                       \
      } else {                                                                \
        xc = xRd[xi];                                                         \
      }                                                                       \
      float c = __builtin_fmaf(w1v0, xa,                                      \
                __builtin_fmaf(w1v1, xb,                                      \
                __builtin_fmaf(w1v2, xc, b1v)));                              \
      c = c > 0.f ? c : 0.f;                                                  \
      if (CLAMP_) c = (xi < 0) ? 0.f : c;                                     \
      uint32_t cu;                                                            \
      asm("v_cvt_pk_bf16_f32 %0, %1, %2" : "=v"(cu) : "v"(c), "v"(c));        \
      c1Wr[i * 16] = (short)(cu & 0xffff);                                    \
      xa = xb; xb = xc;                                                       \
    }                                                                         \
  } while (0)

#define CONV2_PHASE() do {                                                    \
    _Pragma("unroll")                                                         \
    for (int i = 0; i < 8; ++i) {                                             \
      const int u = ub + i;                                                   \
      s16x8 a0 = *reinterpret_cast<const s16x8*>(c1Rd + u * 16);              \
      s16x8 a1 = *reinterpret_cast<const s16x8*>(c1Rd + u * 16 + 32);         \
      f32x4 sa = MFMA16(a1, cW2[1], MFMA16(a0, cW2[0], b2v4));                \
      float m0 = sa[0] > 0.f ? sa[0] : 0.f;                                   \
      float m1 = sa[1] > 0.f ? sa[1] : 0.f;                                   \
      float m2 = sa[2] > 0.f ? sa[2] : 0.f;                                   \
      float m3 = sa[3] > 0.f ? sa[3] : 0.f;                                   \
      uint32_t u01, u23;                                                      \
      asm("v_cvt_pk_bf16_f32 %0, %1, %2" : "=v"(u01) : "v"(m0), "v"(m1));     \
      asm("v_cvt_pk_bf16_f32 %0, %1, %2" : "=v"(u23) : "v"(m2), "v"(m3));     \
      sWr[u * 640 +   0] = (short)(u01 & 0xffff);                             \
      sWr[u * 640 +  40] = (short)(u01 >> 16);                                \
      sWr[u * 640 +  80] = (short)(u23 & 0xffff);                             \
      sWr[u * 640 + 120] = (short)(u23 >> 16);                                \
    }                                                                         \
  } while (0)

#define GSTEP(TL) do {                                                        \
    const int rb_ = (TL) & 1, wb_ = rb_ ^ 1;                                  \
    s16x8 ah0 = *reinterpret_cast<const s16x8*>(hRd + rb_ * 1152);            \
    s16x8 ah1 = *reinterpret_cast<const s16x8*>(hRd + rb_ * 1152 + 32);       \
    __builtin_amdgcn_s_setprio(1);                                            \
    f32x4 sr = MFMA16(asv, WihHi[0], bias_r);    /* s-only, issues early */   \
    f32x4 sz = MFMA16(asv, WihHi[1], bias_z);                                 \
    f32x4 xn = MFMA16(asv, WihHi[2], bias_xn);                                \
    f32x4 pr = MFMA16(ah1, WhhHi[0][1],          /* 2-deep after h-read */    \
               MFMA16(ah0, WhhHi[0][0], sr));                                 \
    f32x4 pz = MFMA16(ah1, WhhHi[1][1],                                       \
               MFMA16(ah0, WhhHi[1][0], sz));                                 \
    f32x4 hn = MFMA16(ah1, WhhHi[2][1],                                       \
               MFMA16(ah0, WhhHi[2][0], bias_hn));                            \
    __builtin_amdgcn_s_setprio(0);                                            \
    asv = *reinterpret_cast<const s16x8*>(sRd + (((TL) + 1) & 15) * 640);     \
    float hnew[4];                                                            \
    _Pragma("unroll")                                                         \
    for (int i2 = 0; i2 < 4; ++i2) {                                          \
      float r = __builtin_amdgcn_rcpf(1.f + __builtin_amdgcn_exp2f(pr[i2]));  \
      float z = __builtin_amdgcn_rcpf(1.f + __builtin_amdgcn_exp2f(pz[i2]));  \
      float arg = __builtin_fmaf(r, hn[i2], xn[i2]);                          \
      float et = __builtin_amdgcn_exp2f(arg);                                 \
      float tn = __builtin_fmaf(-2.f, __builtin_amdgcn_rcpf(et + 1.f), 1.f);  \
      float h = __builtin_fmaf(z, hreg[i2] - tn, tn);                         \
      hreg[i2] = h; hnew[i2] = h;                                             \
    }                                                                         \
    uint32_t p01, p23;                                                        \
    asm("v_cvt_pk_bf16_f32 %0, %1, %2" : "=v"(p01) : "v"(hnew[0]), "v"(hnew[1])); \
    asm("v_cvt_pk_bf16_f32 %0, %1, %2" : "=v"(p23) : "v"(hnew[2]), "v"(hnew[3])); \
    hWr[wb_ * 1152 +   0] = (short)(p01 & 0xffff);                            \
    hWr[wb_ * 1152 +  72] = (short)(p01 >> 16);                               \
    hWr[wb_ * 1152 + 144] = (short)(p23 & 0xffff);                            \
    hWr[wb_ * 1152 + 216] = (short)(p23 >> 16);                               \
    __syncthreads();                                                          \
  } while (0)

#define G16 do { asv = *reinterpret_cast<const s16x8*>(sRd);                  \
                 GSTEP(0);  GSTEP(1);  GSTEP(2);  GSTEP(3);                   \
                 GSTEP(4);  GSTEP(5);  GSTEP(6);  GSTEP(7);                   \
                 GSTEP(8);  GSTEP(9);  GSTEP(10); GSTEP(11);                  \
                 GSTEP(12); GSTEP(13); GSTEP(14); GSTEP(15); } while (0)

  // ---- chunk 0 (edge-clamped conv1) ----
  CONV1_PHASE(0, true);
  __syncthreads();
  CONV2_PHASE();
  __syncthreads();
  G16;

  // ---- chunks 1..5 (no clamps) ----
#pragma unroll 1
  for (int k = 1; k < 6; ++k) {
    const int t0 = k * 16;
    CONV1_PHASE(t0, false);
    __syncthreads();
    CONV2_PHASE();
    __syncthreads();
    G16;
  }

  // ---- chunk 6 (edge-clamped, 4 steps) ----
  CONV1_PHASE(96, true);
  __syncthreads();
  CONV2_PHASE();
  __syncthreads();
  asv = *reinterpret_cast<const s16x8*>(sRd);
  GSTEP(0); GSTEP(1); GSTEP(2); GSTEP(3);

#pragma unroll
  for (int i2 = 0; i2 < 4; ++i2) {
    out[(size_t)(seq0 + lg * 4 + i2) * 64 + 16 * wv + l15] = hreg[i2];
  }
}

extern "C" void kernel_launch(void* const* d_in, const int* in_sizes, int n_in,
                              void* d_out, int out_size, void* d_ws, size_t ws_size,
                              hipStream_t stream)
{
  (void)in_sizes; (void)n_in; (void)d_ws; (void)ws_size; (void)out_size;
  const float* x   = (const float*)d_in[0];
  const float* w1  = (const float*)d_in[1];
  const float* b1  = (const float*)d_in[2];
  const float* w2  = (const float*)d_in[3];
  const float* b2  = (const float*)d_in[4];
  const float* Wih = (const float*)d_in[5];
  const float* Whh = (const float*)d_in[6];
  const float* bih = (const float*)d_in[7];
  const float* bhh = (const float*)d_in[8];
  float* out = (float*)d_out;
  te_fused<<<512, 256, 0, stream>>>(x, w1, b1, w2, b2, Wih, Whh, bih, bhh, out);
}